// Round 9
// baseline (227.966 us; speedup 1.0000x reference)
//
#include <hip/hip_runtime.h>
#include <hip/hip_bf16.h>

#define S_LEN 4096
#define NH 4
#define HD 256
#define WIN 512
#define ATT_SCALE 0.0625f   // 256^-0.5
#define QKV_N 1536          // packed q(1024) | k(256) | v(256) — v cols never written

typedef short s16x8 __attribute__((ext_vector_type(8)));
typedef float f32x4 __attribute__((ext_vector_type(4)));

static __device__ inline unsigned short f2bf(float f) {
  union { float f; unsigned int u; } v; v.f = f;
  unsigned int r = v.u + 0x7fff + ((v.u >> 16) & 1);   // RNE
  return (unsigned short)(r >> 16);
}
static __device__ inline void gl2lds16(const void* g, void* l) {
  __builtin_amdgcn_global_load_lds(
      (const __attribute__((address_space(1))) unsigned int*)g,
      (__attribute__((address_space(3))) unsigned int*)l, 16, 0, 0);
}

// ---------------------------------------------------------------------------
// Fused prep: [0,5120) x fp32->bf16; 4 weight transpose+cast regions;
// [5520,7568) cos/sin -> packed float2 table (csb overlays the aob region,
// which attention overwrites later — safe, and saves workspace).
// ---------------------------------------------------------------------------
static __device__ void trcast_tile(const float* __restrict__ src,
                                   unsigned short* __restrict__ dst,
                                   int K, int N, int bn, int bk, int tid,
                                   float* ts /*[64][65]*/) {
#pragma unroll
  for (int it = 0; it < 4; ++it) {
    const int c = it * 256 + tid;
    const int row = c >> 4, col4 = (c & 15) << 2;
    const float4 v = *(const float4*)(src + (size_t)(bk * 64 + row) * N + bn * 64 + col4);
    ts[row * 65 + col4 + 0] = v.x; ts[row * 65 + col4 + 1] = v.y;
    ts[row * 65 + col4 + 2] = v.z; ts[row * 65 + col4 + 3] = v.w;
  }
  __syncthreads();
#pragma unroll
  for (int it = 0; it < 4; ++it) {
    const int c = it * 256 + tid;
    const int nrow = c >> 4, kc4 = (c & 15) << 2;
    const unsigned int p0 = f2bf(ts[(kc4 + 0) * 65 + nrow]) | ((unsigned int)f2bf(ts[(kc4 + 1) * 65 + nrow]) << 16);
    const unsigned int p1 = f2bf(ts[(kc4 + 2) * 65 + nrow]) | ((unsigned int)f2bf(ts[(kc4 + 3) * 65 + nrow]) << 16);
    *(uint2*)(dst + (size_t)(bn * 64 + nrow) * K + bk * 64 + kc4) = make_uint2(p0, p1);
  }
}

__global__ __launch_bounds__(256) void prep_kernel(
    const float* __restrict__ x, unsigned short* __restrict__ xb,
    const float* __restrict__ Wq, const float* __restrict__ Wk,
    const float* __restrict__ Wv, const float* __restrict__ Wo,
    unsigned short* __restrict__ Wqkvt, unsigned short* __restrict__ Wot,
    const float* __restrict__ cosb, const float* __restrict__ sinb,
    float2* __restrict__ csb) {
  __shared__ float ts[64 * 65];
  const int g = blockIdx.x;
  const int tid = threadIdx.x;
  if (g < 5120) {                    // cvt x -> bf16
    const int t = g * 256 + tid;
    const float4 v = ((const float4*)x)[t];
    const unsigned int p0 = f2bf(v.x) | ((unsigned int)f2bf(v.y) << 16);
    const unsigned int p1 = f2bf(v.z) | ((unsigned int)f2bf(v.w) << 16);
    *(uint2*)(xb + (size_t)t * 4) = make_uint2(p0, p1);
  } else if (g < 5280) {             // Wq
    const int g2 = g - 5120;
    trcast_tile(Wq, Wqkvt, 640, 1024, g2 & 15, g2 >> 4, tid, ts);
  } else if (g < 5320) {             // Wk
    const int g2 = g - 5280;
    trcast_tile(Wk, Wqkvt + (size_t)1024 * 640, 640, 256, g2 & 3, g2 >> 2, tid, ts);
  } else if (g < 5360) {             // Wv
    const int g2 = g - 5320;
    trcast_tile(Wv, Wqkvt + (size_t)1280 * 640, 640, 256, g2 & 3, g2 >> 2, tid, ts);
  } else if (g < 5520) {             // Wo
    const int g2 = g - 5360;
    trcast_tile(Wo, Wot, 1024, 640, g2 % 10, g2 / 10, tid, ts);
  } else {                           // cos/sin float2 table (524288 entries)
    const int t = (g - 5520) * 256 + tid;
    csb[t] = make_float2(cosb[t], sinb[t]);
  }
}

// ---------------------------------------------------------------------------
// Fused QKV GEMM + RMSNorm + RoPE + V-transpose.
// C = xb[8192,640] @ Wqkvt[1536,640]^T, 64x256 tiles, BK=32, grid (6,128).
// bn 0..3 = q heads (qw, *ATT_SCALE), bn 4 = k (kw), bn 5 = v (-> vtb only).
// Fragment-order LDS staging (lane-contiguous ds_read_b128, conflict-free):
// chunk c = 1KB; c<4: A m-strip c; c>=4: B n-strip c-4. Wave (wr=w&1,wc=w>>1)
// owns rows wr*32..+31 x cols wc*128..+127.
// ---------------------------------------------------------------------------
__global__ __launch_bounds__(256) void gemm_qkv_fused(
    const unsigned short* __restrict__ A, const unsigned short* __restrict__ Bt,
    const float2* __restrict__ csb,
    const float* __restrict__ qw, const float* __restrict__ kw,
    unsigned short* __restrict__ qkvb, unsigned short* __restrict__ vtb) {
  __shared__ unsigned short sm[16512];    // 20 chunks (10240) in loop; 64x258 vt buf in epilogue
  __shared__ float red[64][2];
  const int tid = threadIdx.x;
  const int wave = tid >> 6, lane = tid & 63;
  const int ln15 = lane & 15, lgr = lane >> 4;
  const int bn = blockIdx.x, bm = blockIdx.y;
  const int wr = wave & 1, wc = wave >> 1;
  const int K = 640;
  const unsigned short* Ab = A + (size_t)bm * 64 * K;
  const unsigned short* Bb = Bt + (size_t)bn * 256 * K;

  f32x4 acc[2][8];
#pragma unroll
  for (int mt = 0; mt < 2; ++mt)
#pragma unroll
    for (int nt = 0; nt < 8; ++nt) acc[mt][nt] = (f32x4){0.f, 0.f, 0.f, 0.f};

  for (int kt = 0; kt < 640; kt += 32) {
#pragma unroll
    for (int u = 0; u < 5; ++u) {
      const int c = wave * 5 + u;
      if (c < 4)
        gl2lds16(Ab + (size_t)(c * 16 + ln15) * K + kt + lgr * 8, &sm[c * 512]);
      else
        gl2lds16(Bb + (size_t)((c - 4) * 16 + ln15) * K + kt + lgr * 8, &sm[c * 512]);
    }
    __syncthreads();
    s16x8 af[2], bfr[8];
#pragma unroll
    for (int mt = 0; mt < 2; ++mt)
      af[mt] = *(const s16x8*)&sm[(wr * 2 + mt) * 512 + lane * 8];
#pragma unroll
    for (int nt = 0; nt < 8; ++nt)
      bfr[nt] = *(const s16x8*)&sm[(4 + wc * 8 + nt) * 512 + lane * 8];
#pragma unroll
    for (int mt = 0; mt < 2; ++mt)
#pragma unroll
      for (int nt = 0; nt < 8; ++nt)
        acc[mt][nt] = __builtin_amdgcn_mfma_f32_16x16x32_bf16(af[mt], bfr[nt], acc[mt][nt], 0, 0, 0);
    __syncthreads();
  }

  if (bn < 5) {
    // ---- rmsnorm + rope epilogue (q heads / k) ----
    const float* w = (bn < 4) ? qw : kw;
    const float scale = (bn < 4) ? ATT_SCALE : 1.0f;
    float part[2][4];
#pragma unroll
    for (int mt = 0; mt < 2; ++mt)
#pragma unroll
      for (int r = 0; r < 4; ++r) {
        float s = 0.f;
#pragma unroll
        for (int nt = 0; nt < 8; ++nt) s += acc[mt][nt][r] * acc[mt][nt][r];
        part[mt][r] = s;
      }
#pragma unroll
    for (int off = 1; off < 16; off <<= 1)
#pragma unroll
      for (int mt = 0; mt < 2; ++mt)
#pragma unroll
        for (int r = 0; r < 4; ++r) part[mt][r] += __shfl_xor(part[mt][r], off);
    if (ln15 == 0) {
#pragma unroll
      for (int mt = 0; mt < 2; ++mt)
#pragma unroll
        for (int r = 0; r < 4; ++r)
          red[wr * 32 + mt * 16 + lgr * 4 + r][wc] = part[mt][r];
    }
    __syncthreads();
#pragma unroll
    for (int mt = 0; mt < 2; ++mt)
#pragma unroll
      for (int r = 0; r < 4; ++r) {
        const int rl = wr * 32 + mt * 16 + lgr * 4 + r;
        const float inv = rsqrtf((red[rl][0] + red[rl][1]) * (1.0f / 256.0f) + 1e-6f);
        const int grow = bm * 64 + rl;
        const int spos = grow & (S_LEN - 1);
#pragma unroll
        for (int nt = 0; nt < 8; ++nt) {
          const int col = wc * 128 + nt * 16 + ln15;       // head-local 0..255
          const float val = acc[mt][nt][r] * inv * (1.0f + w[col]);
          const float prt = __shfl_xor(val, 1);
          const float2 cs = csb[spos * 128 + (col >> 1)];
          float o = (ln15 & 1) ? (prt * cs.y + val * cs.x)   // odd col: a*s + b*c
                               : (val * cs.x - prt * cs.y);  // even col: a*c - b*s
          qkvb[(size_t)grow * QKV_N + bn * 256 + col] = f2bf(o * scale);
        }
      }
  } else {
    // ---- v path: interleaved transpose straight to vtb (skip qkvb) ----
#pragma unroll
    for (int mt = 0; mt < 2; ++mt)
#pragma unroll
      for (int nt = 0; nt < 8; ++nt)
#pragma unroll
        for (int r = 0; r < 4; ++r) {
          const float val = acc[mt][nt][r];
          const float prt = __shfl_xor(val, 1);   // odd-col partner
          if (!(ln15 & 1)) {
            const int j = wr * 32 + mt * 16 + lgr * 4 + r;
            const int d = wc * 128 + nt * 16 + ln15;        // even
            *(unsigned int*)&sm[j * 258 + d] =
                (unsigned int)f2bf(val) | ((unsigned int)f2bf(prt) << 16);
          }
        }
    __syncthreads();
    const int bb = bm >> 6;
    const int jt0 = (bm & 63) * 2;
#pragma unroll
    for (int half = 0; half < 2; ++half) {
      unsigned short tmp[32];
#pragma unroll
      for (int s2 = 0; s2 < 32; ++s2) {
        const int jj = (s2 >> 1) | ((s2 & 1) << 4);   // interleave: key i -> col 2i / 2i+1
        tmp[s2] = sm[(half * 32 + jj) * 258 + tid];
      }
      unsigned short* dst = vtb + ((size_t)(bb * 128 + jt0 + half) * 256 + tid) * 32;
#pragma unroll
      for (int wq = 0; wq < 4; ++wq) *(uint4*)(dst + wq * 8) = *(uint4*)(tmp + wq * 8);
    }
  }
}

// ---------------------------------------------------------------------------
// Output projection: C[M,640] = aob[M,1024] @ Wot[640,1024]^T.
// 64x128 tile, BK=32, fragment-order staging (conflict-free), grid (5,128).
// ---------------------------------------------------------------------------
__global__ __launch_bounds__(256) void gemm_bt64(const unsigned short* __restrict__ A,
                                                 const unsigned short* __restrict__ Bt,
                                                 float* __restrict__ C,
                                                 int M, int N, int K) {
  __shared__ unsigned short sm[12 * 512];
  const int tid = threadIdx.x;
  const int wave = tid >> 6, lane = tid & 63;
  const int ln15 = lane & 15, lgr = lane >> 4;
  const int bm = blockIdx.y, bn = blockIdx.x;
  const unsigned short* Ab = A + (size_t)bm * 64 * K;
  const unsigned short* Bb = Bt + (size_t)bn * 128 * K;

  f32x4 acc[4][2];
#pragma unroll
  for (int mt = 0; mt < 4; ++mt)
#pragma unroll
    for (int nt = 0; nt < 2; ++nt) acc[mt][nt] = (f32x4){0.f, 0.f, 0.f, 0.f};

  for (int kt = 0; kt < K; kt += 32) {
#pragma unroll
    for (int u = 0; u < 3; ++u) {
      const int c = wave * 3 + u;
      if (c < 4)
        gl2lds16(Ab + (size_t)(c * 16 + ln15) * K + kt + lgr * 8, &sm[c * 512]);
      else
        gl2lds16(Bb + (size_t)((c - 4) * 16 + ln15) * K + kt + lgr * 8, &sm[c * 512]);
    }
    __syncthreads();
    s16x8 af[4], bfr[2];
#pragma unroll
    for (int t = 0; t < 4; ++t)
      af[t] = *(const s16x8*)&sm[t * 512 + lane * 8];
#pragma unroll
    for (int t = 0; t < 2; ++t)
      bfr[t] = *(const s16x8*)&sm[(4 + wave * 2 + t) * 512 + lane * 8];
#pragma unroll
    for (int mt = 0; mt < 4; ++mt)
#pragma unroll
      for (int nt = 0; nt < 2; ++nt)
        acc[mt][nt] = __builtin_amdgcn_mfma_f32_16x16x32_bf16(af[mt], bfr[nt], acc[mt][nt], 0, 0, 0);
    __syncthreads();
  }

#pragma unroll
  for (int mt = 0; mt < 4; ++mt)
#pragma unroll
    for (int nt = 0; nt < 2; ++nt)
#pragma unroll
      for (int r = 0; r < 4; ++r) {
        const size_t row = bm * 64 + mt * 16 + lgr * 4 + r;
        const size_t col = bn * 128 + wave * 32 + nt * 16 + ln15;
        C[row * N + col] = acc[mt][nt][r];
      }
}

// ---------------------------------------------------------------------------
// Flash-style sliding-window MQA, bf16 MFMA — R6 version (best measured).
// 64-row q-tile, 16 rows/wave, 512 blocks = 2/CU (two independent blocks/CU
// hide each other's barrier drains — R7's 1 block/CU regressed 1.4x).
// ---------------------------------------------------------------------------
#define PS_LD 40

__global__ __launch_bounds__(256) void attn_mfma_kernel(
    const unsigned short* __restrict__ qkv, const unsigned short* __restrict__ vtb,
    unsigned short* __restrict__ aob) {
  const int g = blockIdx.x;
  const int xcd = g & 7, slot = g >> 3;      // assume block j -> XCD j%8
  const int h = slot >> 4;                   // 0..3
  const int qt = xcd * 16 + (slot & 15);     // 0..127
  const int b = qt >> 6;
  const int q0 = (qt & 63) << 6;
  const int tid = threadIdx.x;
  const int wave = tid >> 6;
  const int lane = tid & 63;
  const int ln15 = lane & 15;
  const int lgr = lane >> 4;

  __shared__ unsigned short Ks[2][16 * 512];
  __shared__ unsigned short Vts[2][16 * 512];
  __shared__ unsigned short Ps[4][16 * PS_LD];

  const size_t qrow = (size_t)(b * S_LEN + q0 + wave * 16 + ln15) * QKV_N + h * HD;
  s16x8 qfrag[8];
#pragma unroll
  for (int f = 0; f < 8; ++f)
    qfrag[f] = *(const s16x8*)(qkv + qrow + f * 32 + lgr * 8);

  f32x4 acc[16];
#pragma unroll
  for (int t = 0; t < 16; ++t) acc[t] = (f32x4){0.f, 0.f, 0.f, 0.f};
  float l_part[4] = {0.f, 0.f, 0.f, 0.f};

  const int kt_lo = max(0, q0 - WIN) >> 5;
  const int kt_hi = (q0 + 63) >> 5;
  const unsigned short* kbase = qkv + (size_t)(b * S_LEN) * QKV_N + 4 * HD;
  const unsigned short* vbase = vtb + (size_t)b * (S_LEN / 32) * HD * 32;

  auto stage = [&](int kt, int buf) {
#pragma unroll
    for (int u = 0; u < 4; ++u) {
      const int c = wave * 4 + u;
      const int ct = c >> 3, f = c & 7;
      const unsigned short* gk =
          kbase + (size_t)(kt * 32 + ct * 16 + ln15) * QKV_N + f * 32 + lgr * 8;
      gl2lds16(gk, &Ks[buf][c * 512]);
      const unsigned short* gv =
          vbase + (size_t)kt * (HD * 32) + (size_t)(c * 16 + ln15) * 32 + lgr * 8;
      gl2lds16(gv, &Vts[buf][c * 512]);
    }
  };

  stage(kt_lo, 0);
  __syncthreads();

  unsigned short* psw = Ps[wave];
  const int i_row0 = q0 + wave * 16 + lgr * 4;

  for (int kt = kt_lo; kt <= kt_hi; ++kt) {
    const int cur = (kt - kt_lo) & 1;
    if (kt < kt_hi) stage(kt + 1, cur ^ 1);

    f32x4 sc[2];
    sc[0] = (f32x4){0.f, 0.f, 0.f, 0.f};
    sc[1] = (f32x4){0.f, 0.f, 0.f, 0.f};
#pragma unroll
    for (int f = 0; f < 8; ++f) {
#pragma unroll
      for (int ct = 0; ct < 2; ++ct) {
        const s16x8 kf = *(const s16x8*)&Ks[cur][(ct * 8 + f) * 512 + lane * 8];
        sc[ct] = __builtin_amdgcn_mfma_f32_16x16x32_bf16(qfrag[f], kf, sc[ct], 0, 0, 0);
      }
    }

    const int j0 = kt * 32 + ln15;
    float p0[4], p1[4];
#pragma unroll
    for (int r = 0; r < 4; ++r) {
      const int i = i_row0 + r;
      const bool a0 = (j0 <= i) && (i - j0 <= WIN);
      const bool a1 = (j0 + 16 <= i) && (i - (j0 + 16) <= WIN);
      const float e0 = __expf(sc[0][r] - 16.0f);
      const float e1 = __expf(sc[1][r] - 16.0f);
      p0[r] = a0 ? e0 : 0.0f;
      p1[r] = a1 ? e1 : 0.0f;
      l_part[r] += p0[r] + p1[r];
    }
#pragma unroll
    for (int r = 0; r < 4; ++r) {
      const unsigned int pk = (unsigned int)f2bf(p0[r]) | ((unsigned int)f2bf(p1[r]) << 16);
      *(unsigned int*)&psw[(lgr * 4 + r) * PS_LD + (ln15 << 1)] = pk;
    }
    const s16x8 pf = *(const s16x8*)&psw[ln15 * PS_LD + lgr * 8];
#pragma unroll
    for (int t = 0; t < 16; ++t) {
      const s16x8 vf = *(const s16x8*)&Vts[cur][t * 512 + lane * 8];
      acc[t] = __builtin_amdgcn_mfma_f32_16x16x32_bf16(pf, vf, acc[t], 0, 0, 0);
    }
    __syncthreads();
  }

#pragma unroll
  for (int off = 1; off < 16; off <<= 1)
#pragma unroll
    for (int r = 0; r < 4; ++r) l_part[r] += __shfl_xor(l_part[r], off);

  float inv_l[4];
#pragma unroll
  for (int r = 0; r < 4; ++r) inv_l[r] = 1.0f / l_part[r];
#pragma unroll
  for (int t = 0; t < 16; ++t)
#pragma unroll
    for (int r = 0; r < 4; ++r) {
      const size_t orow = (size_t)(b * S_LEN + q0 + wave * 16 + lgr * 4 + r);
      aob[(orow * NH + h) * HD + t * 16 + ln15] = f2bf(acc[t][r] * inv_l[r]);
    }
}

// ---------------------------------------------------------------------------
extern "C" void kernel_launch(void* const* d_in, const int* in_sizes, int n_in,
                              void* d_out, int out_size, void* d_ws, size_t ws_size,
                              hipStream_t stream) {
  const float* x    = (const float*)d_in[0];
  const float* cosb = (const float*)d_in[1];
  const float* sinb = (const float*)d_in[2];
  const float* Wq   = (const float*)d_in[3];
  const float* Wk   = (const float*)d_in[4];
  const float* Wv   = (const float*)d_in[5];
  const float* Wo   = (const float*)d_in[6];
  const float* qw   = (const float*)d_in[7];
  const float* kw   = (const float*)d_in[8];
  float* out = (float*)d_out;

  unsigned short* ws = (unsigned short*)d_ws;
  unsigned short* xb     = ws;                    // 8192*640  = 5242880 u16
  unsigned short* Wqkvt  = xb + 5242880;          // 1536*640  = 983040
  unsigned short* Wot    = Wqkvt + 983040;        // 640*1024  = 655360
  unsigned short* qkvb   = Wot + 655360;          // 8192*1536 = 12582912
  unsigned short* vtb    = qkvb + 12582912;       // 8192*256  = 2097152
  unsigned short* aob    = vtb + 2097152;         // 8192*1024 = 8388608 (16 MB)
  float2* csb = (float2*)aob;   // 4 MB cos/sin table; aob overwritten by attn later
  const int M = 2 * S_LEN;

  prep_kernel<<<7568, 256, 0, stream>>>(x, xb, Wq, Wk, Wv, Wo, Wqkvt, Wot,
                                        cosb, sinb, csb);
  gemm_qkv_fused<<<dim3(6, M / 64), 256, 0, stream>>>(xb, Wqkvt, csb, qw, kw,
                                                      qkvb, vtb);
  attn_mfma_kernel<<<M / 64 * NH, 256, 0, stream>>>(qkvb, vtb, aob);
  gemm_bt64<<<dim3(640 / 128, M / 64), 256, 0, stream>>>(aob, Wot, out, M, 640, 1024);
}